// Round 3
// baseline (92.128 us; speedup 1.0000x reference)
//
#include <hip/hip_runtime.h>
#include <stdint.h>

// Problem constants
#define NB 32768   // batch
#define NN 128     // stages

typedef __attribute__((ext_vector_type(8))) short bf16x8;
typedef __attribute__((ext_vector_type(4))) float f32x4;

__device__ __forceinline__ uint16_t f2bf(float v) {
    uint32_t u = __float_as_uint(v);
    u += 0x7FFF + ((u >> 16) & 1);   // RNE
    return (uint16_t)(u >> 16);
}

// Fully fused kernel. Math:
//   phi[r][k] = prod_{j>=k}(1-2x_j)  (suffix parity, via ballot)
//   x_out[r][m] = 1-2*sigmoid( prod_{kx<8}( phi[r]·Wx[m*8+kx] + bx ) )
//   raw_y[r][mk] = xo*( sum_{k<64} phi_k Wy[mk][k] + phi_64*Wy[mk][64] )
//                + |xo|*( sum_{k>=64} phi_k Wy[mk][k+1] + Wy[mk][129] )
//   out[m][r] = sigmoid( prod_{ky<8} raw_y[r][m*8+ky] )
__global__ __launch_bounds__(512, 2) void puf_fused(
    const float* __restrict__ x, const float* __restrict__ Wx,
    const float* __restrict__ bx, const float* __restrict__ Wy,
    float* __restrict__ out)
{
    __shared__ uint16_t As[128 * 128];  // 32KB phi tile (swizzled, ±1 bf16)
    __shared__ uint16_t Bs[256 * 128];  // 64KB: B1 [256][128], then B2 [512][64]
    __shared__ float    Xo[128 * 32];   // 16KB x_out[row][m]
    __shared__ float    Sg[128];        // phi[r][64] sign (float ±1)

    const int tid = threadIdx.x;
    const int w   = tid >> 6, l = tid & 63;
    const int wr  = w >> 2, wc = w & 3;     // row-half / col-quarter of this wave
    const int l15 = l & 15, l4 = l >> 4;
    const int row0 = blockIdx.x * 128;

    // early scattered preloads (L2-resident): bias + pivot + const weights per col-frag
    float bxv[4], epsv[4], pivv[4];
#pragma unroll
    for (int cf = 0; cf < 4; ++cf) {
        int c = wc * 64 + cf * 16 + l15;
        bxv[cf]  = bx[c];
        pivv[cf] = Wy[c * 130 + 64];
        epsv[cf] = Wy[c * 130 + 129];
    }

    // ---------------- Phase A: phi features via ballot parity ----------------
    float xa[16], xb[16];
#pragma unroll
    for (int i = 0; i < 16; ++i) {
        int grow = row0 + w * 16 + i;
        xa[i] = x[grow * NN + l];
        xb[i] = x[grow * NN + 64 + l];
    }
#pragma unroll
    for (int i = 0; i < 16; ++i) {
        int r = w * 16 + i;
        unsigned long long m0 = __ballot(xa[i] > 0.5f);  // bits: x[r][0..63]
        unsigned long long m1 = __ballot(xb[i] > 0.5f);  // bits: x[r][64..127]
        int onesHi = __popcll(m1);
        int parLo = (__popcll(m0 >> l) + onesHi) & 1;    // parity of x[r][l..127]
        int parHi = (__popcll(m1 >> l)) & 1;             // parity of x[r][64+l..127]
        uint16_t blo = parLo ? 0xBF80u : 0x3F80u;        // -1 / +1 in bf16
        uint16_t bhi = parHi ? 0xBF80u : 0x3F80u;
        int sw = (r & 7) << 3;
        As[r * 128 + (l ^ sw)]        = blo;             // elem l
        As[r * 128 + (64 + (l ^ sw))] = bhi;             // elem 64+l
        if (l == 0) Sg[r] = (onesHi & 1) ? -1.0f : 1.0f; // phi[r][64]
    }

    // ---------------- B1 weight build: Bs[c][k] = bf16(Wx[c][k]), swizzled ----------------
    {
        const int c  = tid >> 1;            // 0..255
        const int hh = tid & 1;             // which 64-col half
        const int swz = (c & 7) << 3;
        const f32x4* wsrc = (const f32x4*)(Wx + c * NN + hh * 64);
#pragma unroll
        for (int seg = 0; seg < 4; ++seg) {
            f32x4 f[4];
#pragma unroll
            for (int j = 0; j < 4; ++j) f[j] = wsrc[seg * 4 + j];
#pragma unroll
            for (int g = 0; g < 2; ++g) {
                bf16x8 pk;
#pragma unroll
                for (int e = 0; e < 8; ++e) pk[e] = (short)f2bf(f[g * 2 + (e >> 2)][e & 3]);
                int k0 = hh * 64 + seg * 16 + g * 8;
                int idx = (k0 & 64) | ((k0 & 63) ^ swz);
                *(bf16x8*)&Bs[c * NN + idx] = pk;
            }
        }
    }
    __syncthreads();

    // ---------------- B1 GEMM: x-arbiter cols [0,256) over k=128 ----------------
    const f32x4 zero4 = {0.0f, 0.0f, 0.0f, 0.0f};
    f32x4 acc1[4][4];
#pragma unroll
    for (int a = 0; a < 4; ++a)
#pragma unroll
        for (int b = 0; b < 4; ++b) acc1[a][b] = zero4;

#pragma unroll
    for (int t = 0; t < 4; ++t) {
        int k = t * 32 + l4 * 8;
        bf16x8 af[4], bf[4];
#pragma unroll
        for (int rf = 0; rf < 4; ++rf) {
            int r = wr * 64 + rf * 16 + l15;
            af[rf] = *(const bf16x8*)&As[r * 128 + ((k & 64) | ((k & 63) ^ ((r & 7) << 3)))];
        }
#pragma unroll
        for (int cf = 0; cf < 4; ++cf) {
            int c = wc * 64 + cf * 16 + l15;
            bf[cf] = *(const bf16x8*)&Bs[c * 128 + ((k & 64) | ((k & 63) ^ ((c & 7) << 3)))];
        }
#pragma unroll
        for (int rf = 0; rf < 4; ++rf)
#pragma unroll
            for (int cf = 0; cf < 4; ++cf)
                acc1[rf][cf] = __builtin_amdgcn_mfma_f32_16x16x32_bf16(af[rf], bf[cf], acc1[rf][cf], 0, 0, 0);
    }
    __syncthreads();  // all waves done reading Bs (B1 view)

    // ---------------- B2 weight build (overwrites Bs as [512][64]) ----------------
    // rows 0..255  (S1): Wy[mk][kk]      for kk in [0,64)   (k_abs = kk)
    // rows 256..511(S2): Wy[mk][65+kk]   for kk in [0,64)   (k_abs = 64+kk)
    {
        const int c2 = tid;                 // 0..511
        const int mk = c2 & 255;
        const float* src = Wy + mk * 130 + ((c2 < 256) ? 0 : 65);
        const int swz = (c2 & 7) << 3;
#pragma unroll
        for (int g = 0; g < 8; ++g) {
            bf16x8 pk;
#pragma unroll
            for (int e = 0; e < 8; ++e) pk[e] = (short)f2bf(src[g * 8 + e]);
            *(bf16x8*)&Bs[c2 * 64 + ((g * 8) ^ swz)] = pk;
        }
    }

    // ---------------- B1 epilogue: x_out -> Xo (wave-local) ----------------
#pragma unroll
    for (int rf = 0; rf < 4; ++rf) {
#pragma unroll
        for (int cf = 0; cf < 4; ++cf) {
            float p[4];
#pragma unroll
            for (int q = 0; q < 4; ++q) p[q] = acc1[rf][cf][q] + bxv[cf];
#pragma unroll
            for (int q = 0; q < 4; ++q) {
                p[q] *= __shfl_xor(p[q], 1);
                p[q] *= __shfl_xor(p[q], 2);
                p[q] *= __shfl_xor(p[q], 4);
            }
            if ((l & 7) == 0) {
                int m = wc * 8 + cf * 2 + (l15 >> 3);
#pragma unroll
                for (int q = 0; q < 4; ++q) {
                    int r = wr * 64 + rf * 16 + l4 * 4 + q;
                    float sig = 1.0f / (1.0f + __expf(-p[q]));
                    Xo[r * 32 + m] = 1.0f - 2.0f * sig;
                }
            }
        }
    }
    __syncthreads();  // B2 weights + Xo ready

    // ---------------- B2 GEMMs: S1 (k<64) and S2 (k>=64) ----------------
    f32x4 accS1[4][4], accS2[4][4];
#pragma unroll
    for (int a = 0; a < 4; ++a)
#pragma unroll
        for (int b = 0; b < 4; ++b) { accS1[a][b] = zero4; accS2[a][b] = zero4; }

#pragma unroll
    for (int t = 0; t < 2; ++t) {
        int kk = t * 32 + l4 * 8;           // k_abs = kk  (< 64)
        bf16x8 af[4], bf[4];
#pragma unroll
        for (int rf = 0; rf < 4; ++rf) {
            int r = wr * 64 + rf * 16 + l15;
            af[rf] = *(const bf16x8*)&As[r * 128 + (kk ^ ((r & 7) << 3))];
        }
#pragma unroll
        for (int cf = 0; cf < 4; ++cf) {
            int c1 = wc * 64 + cf * 16 + l15;
            bf[cf] = *(const bf16x8*)&Bs[c1 * 64 + (kk ^ ((c1 & 7) << 3))];
        }
#pragma unroll
        for (int rf = 0; rf < 4; ++rf)
#pragma unroll
            for (int cf = 0; cf < 4; ++cf)
                accS1[rf][cf] = __builtin_amdgcn_mfma_f32_16x16x32_bf16(af[rf], bf[cf], accS1[rf][cf], 0, 0, 0);
    }
#pragma unroll
    for (int t = 0; t < 2; ++t) {
        int kk = t * 32 + l4 * 8;           // k_abs = 64 + kk
        bf16x8 af[4], bf[4];
#pragma unroll
        for (int rf = 0; rf < 4; ++rf) {
            int r = wr * 64 + rf * 16 + l15;
            af[rf] = *(const bf16x8*)&As[r * 128 + (64 | (kk ^ ((r & 7) << 3)))];
        }
#pragma unroll
        for (int cf = 0; cf < 4; ++cf) {
            int c1 = wc * 64 + cf * 16 + l15;
            bf[cf] = *(const bf16x8*)&Bs[(256 + c1) * 64 + (kk ^ ((c1 & 7) << 3))];
        }
#pragma unroll
        for (int rf = 0; rf < 4; ++rf)
#pragma unroll
            for (int cf = 0; cf < 4; ++cf)
                accS2[rf][cf] = __builtin_amdgcn_mfma_f32_16x16x32_bf16(af[rf], bf[cf], accS2[rf][cf], 0, 0, 0);
    }

    // ---------------- B2 epilogue: combine, product over ky, sigmoid, store ----------------
#pragma unroll
    for (int rf = 0; rf < 4; ++rf) {
#pragma unroll
        for (int cf = 0; cf < 4; ++cf) {
            int m = wc * 8 + cf * 2 + (l15 >> 3);
            float p[4];
#pragma unroll
            for (int q = 0; q < 4; ++q) {
                int r = wr * 64 + rf * 16 + l4 * 4 + q;
                float xo  = Xo[r * 32 + m];
                float axo = fabsf(xo);
                float s1 = accS1[rf][cf][q] + Sg[r] * pivv[cf];
                float s2 = accS2[rf][cf][q] + epsv[cf];
                p[q] = xo * s1 + axo * s2;
            }
#pragma unroll
            for (int q = 0; q < 4; ++q) {
                p[q] *= __shfl_xor(p[q], 1);
                p[q] *= __shfl_xor(p[q], 2);
                p[q] *= __shfl_xor(p[q], 4);
            }
            if ((l & 7) == 0) {
                f32x4 o;
#pragma unroll
                for (int q = 0; q < 4; ++q) o[q] = 1.0f / (1.0f + __expf(-p[q]));
                int rbase = row0 + wr * 64 + rf * 16 + l4 * 4;
                *(f32x4*)&out[m * NB + rbase] = o;
            }
        }
    }
}

extern "C" void kernel_launch(void* const* d_in, const int* in_sizes, int n_in,
                              void* d_out, int out_size, void* d_ws, size_t ws_size,
                              hipStream_t stream) {
    const float* x  = (const float*)d_in[0];
    const float* Wx = (const float*)d_in[1];
    const float* bx = (const float*)d_in[2];
    const float* Wy = (const float*)d_in[3];
    float* out = (float*)d_out;
    (void)d_ws; (void)ws_size;

    puf_fused<<<dim3(256), dim3(512), 0, stream>>>(x, Wx, bx, Wy, out);
}